// Round 1
// baseline (451.069 us; speedup 1.0000x reference)
//
#include <hip/hip_runtime.h>

#define DEV static __device__ __forceinline__

struct Cx { float r, i; };
DEV Cx cmul(Cx a, Cx b){ Cx o; o.r = a.r*b.r - a.i*b.i; o.i = a.r*b.i + a.i*b.r; return o; }

// ---- DPP helpers (row = 16 lanes) ----
template<int CTRL>
DEV float dppf(float x){
  int v = __builtin_amdgcn_update_dpp(0, __builtin_bit_cast(int, x), CTRL, 0xF, 0xF, true);
  return __builtin_bit_cast(float, v);
}
// sum over each 16-lane row; every lane of the row gets the full row sum
DEV float rowsum16(float v){
  v += dppf<0xB1>(v);    // quad_perm(1,0,3,2): xor 1
  v += dppf<0x4E>(v);    // quad_perm(2,3,0,1): xor 2
  v += dppf<0x124>(v);   // row_ror:4
  v += dppf<0x128>(v);   // row_ror:8
  return v;
}

DEV float fexp(float x){ return __builtin_amdgcn_exp2f(x * 1.44269504088896341f); }
DEV float frcp(float x){ return __builtin_amdgcn_rcpf(x); }
DEV float frsq(float x){ return __builtin_amdgcn_rsqf(x); }
DEV float fsqrt_(float x){ return __builtin_amdgcn_sqrtf(x); }
DEV float sigmoidf_(float x){ return frcp(1.f + fexp(-x)); }
DEV float tanhfast(float x){ return 1.f - 2.f*frcp(1.f + fexp(2.f*x)); }

// qubit i <-> bit (3-i) of the 16-amplitude index.
__global__ void __launch_bounds__(64) qssm(
  const float* __restrict__ x,  const float* __restrict__ fw,
  const float* __restrict__ ew, const float* __restrict__ eb,
  const float* __restrict__ exw,const float* __restrict__ exb,
  const float* __restrict__ vw, const float* __restrict__ nrw,
  const float* __restrict__ nrb,float* __restrict__ out,
  int T, long long hToff)
{
  const int lane = threadIdx.x;     // 0..63
  const int blk  = blockIdx.x;      // batch element
  const int s    = lane & 15;       // segment for entry dot
  const int qc   = lane >> 4;       // qubit row (dot) / chunk (matvec)
  const int k    = lane & 15;       // amplitude index

  // ---------- build fixed circuit matrix M (16x16 complex) once ----------
  __shared__ float MrS[16][16];
  __shared__ float MiS[16][16];
  if (lane < 16){
    const int j = lane;             // simulate column j
    float w2[2][3][4];
    #pragma unroll
    for (int l=0;l<2;l++)
      #pragma unroll
      for (int g=0;g<3;g++)
        #pragma unroll
        for (int i=0;i<4;i++) w2[l][g][i] = 0.5f * vw[(l*3+g)*4+i];
    float sr[16], si[16];
    #pragma unroll
    for (int n=0;n<16;n++){ sr[n] = (n==j)?1.f:0.f; si[n]=0.f; }
    #pragma unroll
    for (int l=0;l<2;l++){
      // CNOT ring: control cq -> target (cq+1)&3, applied cq=0..3 in order
      #pragma unroll
      for (int cq=0;cq<4;cq++){
        const int tq=(cq+1)&3, mc=1<<(3-cq), mt=1<<(3-tq);
        #pragma unroll
        for (int n=0;n<16;n++){
          if ((n&mc) && !(n&mt)){
            const int n1 = n|mt;
            float tr=sr[n], ti=si[n];
            sr[n]=sr[n1]; si[n]=si[n1];
            sr[n1]=tr;    si[n1]=ti;
          }
        }
      }
      // per-qubit Rx,Ry,Rz (fixed angles)
      #pragma unroll
      for (int i=0;i<4;i++){
        const int m=1<<(3-i);
        const float cx=cosf(w2[l][0][i]), sx=sinf(w2[l][0][i]);
        const float cy=cosf(w2[l][1][i]), sy=sinf(w2[l][1][i]);
        const float cz=cosf(w2[l][2][i]), sz=sinf(w2[l][2][i]);
        #pragma unroll
        for (int n=0;n<16;n++){
          if (!(n&m)){
            const int n1=n|m;
            float a0r=sr[n], a0i=si[n], a1r=sr[n1], a1i=si[n1];
            // Rx: [[c,-is],[-is,c]]
            float b0r = cx*a0r + sx*a1i, b0i = cx*a0i - sx*a1r;
            float b1r = sx*a0i + cx*a1r, b1i = -sx*a0r + cx*a1i;
            // Ry: [[c,-s],[s,c]]
            float c0r = cy*b0r - sy*b1r, c0i = cy*b0i - sy*b1i;
            float c1r = sy*b0r + cy*b1r, c1i = sy*b0i + cy*b1i;
            // Rz: diag(e^{-iθ/2}, e^{+iθ/2})
            sr[n]  = cz*c0r + sz*c0i;  si[n]  = cz*c0i - sz*c0r;
            sr[n1] = cz*c1r - sz*c1i;  si[n1] = cz*c1i + sz*c1r;
          }
        }
      }
    }
    #pragma unroll
    for (int n=0;n<16;n++){ MrS[n][j]=sr[n]; MiS[n][j]=si[n]; }
  }
  __syncthreads();

  float Mr[4], Mi[4];
  #pragma unroll
  for (int m=0;m<4;m++){ Mr[m]=MrS[k][4*qc+m]; Mi[m]=MiS[k][4*qc+m]; }

  // ---------- per-lane weight registers ----------
  // entry row qc, x-cols 8s..8s+7 (feature scale exp(fw) folded in), h-cols 4s..4s+3
  float Wx[8], Wh[4];
  #pragma unroll
  for (int m=0;m<8;m++){
    const int col = 8*s+m;
    Wx[m] = ew[qc*192 + col] * fexp(fw[col]);
  }
  #pragma unroll
  for (int m=0;m<4;m++) Wh[m] = ew[qc*192 + 128 + 4*s + m];
  const float ybias = eb[qc];

  // exit rows: lane -> g_lane, i_lane, d_lane
  float Wo0[4], Wo1[4], Wo2[4];
  #pragma unroll
  for (int m=0;m<4;m++){
    Wo0[m] = exw[(lane      )*4+m];
    Wo1[m] = exw[(64  + lane)*4+m];
    Wo2[m] = exw[(128 + lane)*4+m];
  }
  const float bo0 = exb[lane], bo1 = exb[64+lane], bo2 = exb[128+lane];
  const float lw = nrw[lane], lb = nrb[lane];

  const float* xp = x + (size_t)blk * T * 128;
  float* op = out + (size_t)blk * T * 64 + lane;

  float xc[8], xn[8];
  #pragma unroll
  for (int m=0;m<8;m++) xc[m] = xp[8*s+m];

  float hseg[4] = {0.f,0.f,0.f,0.f};   // h[4s..4s+3] from previous step
  float cst = 0.f;                     // c_lane
  float h   = 0.f;                     // h_lane
  const float INVS2 = 0.70710678118654752f;

  for (int t=0; t<T; ++t){
    // prefetch next x_t (latency hidden under this step)
    const int tn = (t+1 < T) ? (t+1) : t;
    #pragma unroll
    for (int m=0;m<8;m++) xn[m] = xp[(size_t)tn*128 + 8*s + m];

    // ---- y_qc = entry dot (192) + bias; DPP reduce within 16-lane row ----
    float acc = Wx[0]*xc[0];
    #pragma unroll
    for (int m=1;m<8;m++) acc = fmaf(Wx[m], xc[m], acc);
    #pragma unroll
    for (int m=0;m<4;m++) acc = fmaf(Wh[m], hseg[m], acc);
    const float y = rowsum16(acc) + ybias;

    const float y0 = __shfl(y, 0),  y1 = __shfl(y, 16),
                y2 = __shfl(y, 32), y3 = __shfl(y, 48);

    // ---- closed-form encoded qubit 2-vectors (no trig):
    // θy=atan(u): cosθ=rsqrt(1+u²); half-angle; θz=atan(u²) likewise.
    Cx v0a,v0b,v1a,v1b,v2a,v2b,v3a,v3b;
    {
      auto mkv = [&](float u, Cx& va, Cx& vb){
        const float r2 = u*u;
        const float c1 = frsq(1.f + r2);
        const float ch = fsqrt_(0.5f*(1.f + c1));
        float sh = fsqrt_(fmaxf(0.5f*(1.f - c1), 0.f));
        sh = copysignf(sh, u);
        const float r4 = r2*r2;
        const float c2 = frsq(1.f + r4);
        const float cz = fsqrt_(0.5f*(1.f + c2));
        const float sz = fsqrt_(fmaxf(0.5f*(1.f - c2), 0.f));
        const float a  = (ch - sh) * INVS2;
        const float bb = (ch + sh) * INVS2;
        va.r = a*cz;  va.i = -a*sz;
        vb.r = bb*cz; vb.i =  bb*sz;
      };
      mkv(y0, v0a, v0b); mkv(y1, v1a, v1b);
      mkv(y2, v2a, v2b); mkv(y3, v3a, v3b);
    }

    // ---- ψ0[j], j = 4*qc + m  (bit3->qubit0, bit2->qubit1, bit1->qubit2, bit0->qubit3)
    Cx sel0, sel1;
    sel0.r = (qc & 2) ? v0b.r : v0a.r;  sel0.i = (qc & 2) ? v0b.i : v0a.i;
    sel1.r = (qc & 1) ? v1b.r : v1a.r;  sel1.i = (qc & 1) ? v1b.i : v1a.i;
    const Cx A  = cmul(sel0, sel1);
    const Cx B0 = cmul(v2a, v3a), B1 = cmul(v2a, v3b),
             B2 = cmul(v2b, v3a), B3 = cmul(v2b, v3b);
    Cx pp[4] = { cmul(A,B0), cmul(A,B1), cmul(A,B2), cmul(A,B3) };

    // ---- F_k = Σ_j M[k][j] ψ0[j] : partial over this lane's 4 j, reduce chunks
    float Fr = 0.f, Fi = 0.f;
    #pragma unroll
    for (int m=0;m<4;m++){
      Fr = fmaf(pp[m].r, Mr[m], Fr); Fr = fmaf(-pp[m].i, Mi[m], Fr);
      Fi = fmaf(pp[m].r, Mi[m], Fi); Fi = fmaf( pp[m].i, Mr[m], Fi);
    }
    Fr += __shfl_xor(Fr, 16); Fr += __shfl_xor(Fr, 32);
    Fi += __shfl_xor(Fi, 16); Fi += __shfl_xor(Fi, 32);

    const float p = Fr*Fr + Fi*Fi;   // probability of amplitude k (replicated x4)

    // ---- Z expectations: pre-signed DPP row-sums; results in every lane
    const float q0 = rowsum16((k & 8) ? -p : p);
    const float q1 = rowsum16((k & 4) ? -p : p);
    const float q2 = rowsum16((k & 2) ? -p : p);
    const float q3 = rowsum16((k & 1) ? -p : p);

    const float z0=y0+q0, z1=y1+q1, z2=y2+q2, z3=y3+q3;

    // ---- exit matvec: lane computes g/i/d raw for hidden index `lane`
    const float og = fmaf(Wo0[0],z0, fmaf(Wo0[1],z1, fmaf(Wo0[2],z2, fmaf(Wo0[3],z3, bo0))));
    const float oi = fmaf(Wo1[0],z0, fmaf(Wo1[1],z1, fmaf(Wo1[2],z2, fmaf(Wo1[3],z3, bo1))));
    const float od = fmaf(Wo2[0],z0, fmaf(Wo2[1],z1, fmaf(Wo2[2],z2, fmaf(Wo2[3],z3, bo2))));

    float g = sigmoidf_(og);
    g = fminf(fmaxf(g, 0.05f), 0.95f);
    const float ig = sigmoidf_(oi);
    const float dt = tanhfast(od);
    cst = (1.f - g)*0.9f*cst + ig*dt;
    const float pre = g * tanhfast(cst);

    // ---- LayerNorm over 64 lanes ----
    float s1 = rowsum16(pre);
    s1 += __shfl_xor(s1, 16); s1 += __shfl_xor(s1, 32);
    float s2 = rowsum16(pre*pre);
    s2 += __shfl_xor(s2, 16); s2 += __shfl_xor(s2, 32);
    const float mu  = s1 * (1.f/64.f);
    const float var = fmaf(s2, 1.f/64.f, -mu*mu);
    const float rstd = frsq(var + 1e-5f);
    h = (pre - mu)*rstd*lw + lb;

    op[(size_t)t*64] = h;

    // gather h[4s..4s+3] for next step's entry dot
    #pragma unroll
    for (int m=0;m<4;m++) hseg[m] = __shfl(h, 4*s + m);

    #pragma unroll
    for (int m=0;m<8;m++) xc[m] = xn[m];
  }

  // final hidden state h_T
  out[hToff + (size_t)blk*64 + lane] = h;
}

extern "C" void kernel_launch(void* const* d_in, const int* in_sizes, int n_in,
                              void* d_out, int out_size, void* d_ws, size_t ws_size,
                              hipStream_t stream)
{
  const float* x   = (const float*)d_in[0];
  const float* fw  = (const float*)d_in[1];
  const float* ew  = (const float*)d_in[2];
  const float* eb  = (const float*)d_in[3];
  const float* exw = (const float*)d_in[4];
  const float* exb = (const float*)d_in[5];
  const float* vw  = (const float*)d_in[6];
  const float* nw  = (const float*)d_in[7];
  const float* nb  = (const float*)d_in[8];

  const long long BT = in_sizes[0] / 128;          // B*T
  const int B = (int)((long long)out_size/64 - BT); // out = B*T*64 + B*64
  const int T = (int)(BT / B);

  qssm<<<B, 64, 0, stream>>>(x, fw, ew, eb, exw, exb, vw, nw, nb,
                             (float*)d_out, T, (long long)BT*64);
}

// Round 4
// 375.483 us; speedup vs baseline: 1.2013x; 1.2013x over previous
//
#include <hip/hip_runtime.h>

#define DEV static __device__ __forceinline__

struct Cx { float r, i; };
DEV Cx cmul(Cx a, Cx b){ Cx o; o.r = a.r*b.r - a.i*b.i; o.i = a.r*b.i + a.i*b.r; return o; }

// ---- DPP helpers (row = 16 lanes). Only modes proven in R1. ----
template<int CTRL>
DEV float dppf(float x){
  int v = __builtin_amdgcn_update_dpp(0, __builtin_bit_cast(int, x), CTRL, 0xF, 0xF, true);
  return __builtin_bit_cast(float, v);
}
// sum over each 16-lane row; every lane of the row gets the full row sum
DEV float rowsum16(float v){
  v += dppf<0xB1>(v);    // quad_perm(1,0,3,2): xor 1
  v += dppf<0x4E>(v);    // quad_perm(2,3,0,1): xor 2
  v += dppf<0x124>(v);   // row_ror:4
  v += dppf<0x128>(v);   // row_ror:8
  return v;
}
// sum over the 4 stride-4 groups within a 16-lane row (keeps lane&3 fixed)
DEV float chunksum4(float v){
  v += dppf<0x124>(v);   // row_ror:4
  v += dppf<0x128>(v);   // row_ror:8
  return v;
}
DEV float rdl(float v, int l){
  return __builtin_bit_cast(float, __builtin_amdgcn_readlane(__builtin_bit_cast(int, v), l));
}
// full 64-lane sum, broadcast to all lanes (rowsum + 4 readlanes + adds)
DEV float full64(float v){
  float r = rowsum16(v);
  return (rdl(r,0) + rdl(r,16)) + (rdl(r,32) + rdl(r,48));
}

DEV float fexp(float x){ return __builtin_amdgcn_exp2f(x * 1.44269504088896341f); }
DEV float frcp(float x){ return __builtin_amdgcn_rcpf(x); }
DEV float frsq(float x){ return __builtin_amdgcn_rsqf(x); }
DEV float fsqrt_(float x){ return __builtin_amdgcn_sqrtf(x); }
DEV float sigmoidf_(float x){ return frcp(1.f + fexp(-x)); }
DEV float tanhfast(float x){ return 1.f - 2.f*frcp(1.f + fexp(2.f*x)); }

// qubit i <-> bit (3-i) of the 16-amplitude index.
__global__ void __launch_bounds__(64) qssm(
  const float* __restrict__ x,  const float* __restrict__ fw,
  const float* __restrict__ ew, const float* __restrict__ eb,
  const float* __restrict__ exw,const float* __restrict__ exb,
  const float* __restrict__ vw, const float* __restrict__ nrw,
  const float* __restrict__ nrb,float* __restrict__ out,
  int T, long long hToff)
{
  const int lane = threadIdx.x;      // 0..63
  const int blk  = blockIdx.x;       // batch element
  const int s    = lane & 15;        // position within 16-row
  const int r    = lane >> 4;        // row
  const int k    = 4*r + (lane & 3); // amplitude this lane owns (F-matvec)
  const int c    = (lane >> 2) & 3;  // j-chunk this lane sums

  // ---------- build fixed circuit matrix M (16x16 complex) once ----------
  __shared__ float MrS[16][16];
  __shared__ float MiS[16][16];
  if (lane < 16){
    const int j = lane;              // simulate column j
    float w2[2][3][4];
    #pragma unroll
    for (int l=0;l<2;l++)
      #pragma unroll
      for (int g=0;g<3;g++)
        #pragma unroll
        for (int i=0;i<4;i++) w2[l][g][i] = 0.5f * vw[(l*3+g)*4+i];
    float sr[16], si[16];
    #pragma unroll
    for (int n=0;n<16;n++){ sr[n] = (n==j)?1.f:0.f; si[n]=0.f; }
    #pragma unroll
    for (int l=0;l<2;l++){
      #pragma unroll
      for (int cq=0;cq<4;cq++){
        const int tq=(cq+1)&3, mc=1<<(3-cq), mt=1<<(3-tq);
        #pragma unroll
        for (int n=0;n<16;n++){
          if ((n&mc) && !(n&mt)){
            const int n1 = n|mt;
            float tr=sr[n], ti=si[n];
            sr[n]=sr[n1]; si[n]=si[n1];
            sr[n1]=tr;    si[n1]=ti;
          }
        }
      }
      #pragma unroll
      for (int i=0;i<4;i++){
        const int m=1<<(3-i);
        const float cx=cosf(w2[l][0][i]), sx=sinf(w2[l][0][i]);
        const float cy=cosf(w2[l][1][i]), sy=sinf(w2[l][1][i]);
        const float cz=cosf(w2[l][2][i]), sz=sinf(w2[l][2][i]);
        #pragma unroll
        for (int n=0;n<16;n++){
          if (!(n&m)){
            const int n1=n|m;
            float a0r=sr[n], a0i=si[n], a1r=sr[n1], a1i=si[n1];
            float b0r = cx*a0r + sx*a1i, b0i = cx*a0i - sx*a1r;
            float b1r = sx*a0i + cx*a1r, b1i = -sx*a0r + cx*a1i;
            float c0r = cy*b0r - sy*b1r, c0i = cy*b0i - sy*b1i;
            float c1r = sy*b0r + cy*b1r, c1i = sy*b0i + cy*b1i;
            sr[n]  = cz*c0r + sz*c0i;  si[n]  = cz*c0i - sz*c0r;
            sr[n1] = cz*c1r - sz*c1i;  si[n1] = cz*c1i + sz*c1r;
          }
        }
      }
    }
    #pragma unroll
    for (int n=0;n<16;n++){ MrS[n][j]=sr[n]; MiS[n][j]=si[n]; }
  }
  __syncthreads();

  // M fragment: row k, columns 4c..4c+3
  float Mr[4], Mi[4];
  #pragma unroll
  for (int m=0;m<4;m++){ Mr[m]=MrS[k][4*c+m]; Mi[m]=MiS[k][4*c+m]; }

  // ---------- per-lane weight registers ----------
  // entry row r (=qubit), x-cols 8s..8s+7, feature scale folded in
  float Wx[8];
  #pragma unroll
  for (int m=0;m<8;m++){
    const int col = 8*s+m;
    Wx[m] = ew[r*192 + col] * fexp(fw[col]);
  }
  const float e0b = eb[0], e1b = eb[1], e2b = eb[2], e3b = eb[3];

  // entry h-columns: Wh_q[lane] for all 4 qubits
  const float lw = nrw[lane], lb = nrb[lane];
  float WL[4], C1[4], C2[4];
  #pragma unroll
  for (int q=0;q<4;q++){
    const float whq = ew[q*192 + 128 + lane];
    WL[q] = whq * lw;
    C1[q] = full64(WL[q]);        // sum_j Wh_q[j]*lw[j]
    C2[q] = full64(whq * lb);     // sum_j Wh_q[j]*lb[j]
  }

  // exit rows: lane -> g_lane, i_lane, d_lane
  float Wo0[4], Wo1[4], Wo2[4];
  #pragma unroll
  for (int m=0;m<4;m++){
    Wo0[m] = exw[(lane      )*4+m];
    Wo1[m] = exw[(64  + lane)*4+m];
    Wo2[m] = exw[(128 + lane)*4+m];
  }
  const float bo0 = exb[lane], bo1 = exb[64+lane], bo2 = exb[128+lane];

  // pre-scaled Z-expectation signs (±0.25: each p_k appears 4x in its row)
  const float sg0 = (lane & 32) ? -0.25f : 0.25f;   // k bit3
  const float sg1 = (lane & 16) ? -0.25f : 0.25f;   // k bit2
  const float sg2 = (lane &  2) ? -0.25f : 0.25f;   // k bit1
  const float sg3 = (lane &  1) ? -0.25f : 0.25f;   // k bit0

  const float* xp = x + (size_t)blk * T * 128;
  float* op = out + (size_t)blk * T * 64 + lane;

  // preamble: Yx for t=0 (x-part of entry dot, per qubit, uniform)
  float Yx0, Yx1, Yx2, Yx3;
  {
    float xr[8];
    #pragma unroll
    for (int m=0;m<8;m++) xr[m] = xp[8*s+m];
    float d0 = fmaf(Wx[1],xr[1], Wx[0]*xr[0]);
    float d1 = fmaf(Wx[3],xr[3], Wx[2]*xr[2]);
    float d2 = fmaf(Wx[5],xr[5], Wx[4]*xr[4]);
    float d3 = fmaf(Wx[7],xr[7], Wx[6]*xr[6]);
    const float rs = rowsum16((d0+d1)+(d2+d3));
    Yx0 = rdl(rs, 0) + e0b; Yx1 = rdl(rs,16) + e1b;
    Yx2 = rdl(rs,32) + e2b; Yx3 = rdl(rs,48) + e3b;
  }

  // recurrent state
  float S0=0.f, S1=0.f, S2=0.f, S3=0.f;   // sum WL_q * pre
  float mu=0.f, rstd=0.f, w0=0.f;         // LN scalars (w0 gates C2 on step 0)
  float cst=0.f, h=0.f;

  for (int t=0; t<T; ++t){
    // ---- y_q = Yx_q + hdot_q ; hdot folded through LayerNorm ----
    const float y0 = Yx0 + fmaf(w0, C2[0], rstd*fmaf(-mu, C1[0], S0));
    const float y1 = Yx1 + fmaf(w0, C2[1], rstd*fmaf(-mu, C1[1], S1));
    const float y2 = Yx2 + fmaf(w0, C2[2], rstd*fmaf(-mu, C1[2], S2));
    const float y3 = Yx3 + fmaf(w0, C2[3], rstd*fmaf(-mu, C1[3], S3));

    // ---- prefetch x(t+1) and compute next Yx (independent of main chain) ----
    {
      const int tn = (t+1 < T) ? (t+1) : t;
      float xr[8];
      #pragma unroll
      for (int m=0;m<8;m++) xr[m] = xp[(size_t)tn*128 + 8*s + m];
      float d0 = fmaf(Wx[1],xr[1], Wx[0]*xr[0]);
      float d1 = fmaf(Wx[3],xr[3], Wx[2]*xr[2]);
      float d2 = fmaf(Wx[5],xr[5], Wx[4]*xr[4]);
      float d3 = fmaf(Wx[7],xr[7], Wx[6]*xr[6]);
      const float rs = rowsum16((d0+d1)+(d2+d3));
      Yx0 = rdl(rs, 0) + e0b; Yx1 = rdl(rs,16) + e1b;
      Yx2 = rdl(rs,32) + e2b; Yx3 = rdl(rs,48) + e3b;
    }

    // exit y-part (parallel with VQC chain)
    const float oy0 = fmaf(Wo0[3],y3, fmaf(Wo0[2],y2, fmaf(Wo0[1],y1, fmaf(Wo0[0],y0, bo0))));
    const float oy1 = fmaf(Wo1[3],y3, fmaf(Wo1[2],y2, fmaf(Wo1[1],y1, fmaf(Wo1[0],y0, bo1))));
    const float oy2 = fmaf(Wo2[3],y3, fmaf(Wo2[2],y2, fmaf(Wo2[1],y1, fmaf(Wo2[0],y0, bo2))));

    // ---- encoded qubit vectors, phase-rotated so va is real ----
    // theta=atan(u): sin=u*rsqrt(1+u^2); a=sqrt((1-sin)/2), b=sqrt((1+sin)/2)
    // phi=atan(u^2): cphi=rsqrt(1+u^4), sphi=u^2*cphi; va=(a,0), vb=b*(cphi,i sphi)
    float a0_,a1_,a2_,a3_;  Cx b0_,b1_,b2_,b3_;
    {
      auto mkv = [&](float u, float& a, Cx& b){
        const float r2 = u*u;
        const float c1 = frsq(fmaf(u,u,1.f));
        const float tt = (0.5f*u)*c1;
        a = fsqrt_(fmaxf(0.5f - tt, 0.f));
        const float bb = fsqrt_(0.5f + tt);
        const float cp = frsq(fmaf(r2,r2,1.f));
        const float sp = r2*cp;
        b.r = bb*cp; b.i = bb*sp;
      };
      mkv(y0,a0_,b0_); mkv(y1,a1_,b1_); mkv(y2,a2_,b2_); mkv(y3,a3_,b3_);
    }

    // ---- psi0[j], j = 4c + m; j bits: (lane&8 -> qubit0 comp, lane&4 -> qubit1) ----
    Cx sel0, sel1;
    sel0.r = (lane & 8) ? b0_.r : a0_;  sel0.i = (lane & 8) ? b0_.i : 0.f;
    sel1.r = (lane & 4) ? b1_.r : a1_;  sel1.i = (lane & 4) ? b1_.i : 0.f;
    const Cx A = cmul(sel0, sel1);
    // B_m = q2vec[m>>1] * q3vec[m&1]
    Cx B0, B1, B2, B3;
    B0.r = a2_*a3_;            B0.i = 0.f;
    B1.r = a2_*b3_.r;          B1.i = a2_*b3_.i;
    B2.r = b2_.r*a3_;          B2.i = b2_.i*a3_;
    B3 = cmul(b2_, b3_);
    const Cx p0 = cmul(A,B0), p1 = cmul(A,B1), p2 = cmul(A,B2), p3 = cmul(A,B3);

    // ---- F_k partial over j=4c..4c+3, then in-row chunk reduction (DPP only) ----
    float t0r = fmaf(-p0.i, Mi[0], p0.r*Mr[0]);
    float t1r = fmaf(-p1.i, Mi[1], p1.r*Mr[1]);
    float t2r = fmaf(-p2.i, Mi[2], p2.r*Mr[2]);
    float t3r = fmaf(-p3.i, Mi[3], p3.r*Mr[3]);
    float t0i = fmaf( p0.i, Mr[0], p0.r*Mi[0]);
    float t1i = fmaf( p1.i, Mr[1], p1.r*Mi[1]);
    float t2i = fmaf( p2.i, Mr[2], p2.r*Mi[2]);
    float t3i = fmaf( p3.i, Mr[3], p3.r*Mi[3]);
    const float Fr = chunksum4((t0r+t1r)+(t2r+t3r));
    const float Fi = chunksum4((t0i+t1i)+(t2i+t3i));

    const float p = fmaf(Fr,Fr, Fi*Fi);   // |F_k|^2, replicated 4x within row

    // ---- Z expectations: signed full-64 sums (DPP + readlane) ----
    const float q0 = full64(sg0*p);
    const float q1 = full64(sg1*p);
    const float q2 = full64(sg2*p);
    const float q3 = full64(sg3*p);

    // ---- exit q-part + gates ----
    const float og = fmaf(Wo0[3],q3, fmaf(Wo0[2],q2, fmaf(Wo0[1],q1, fmaf(Wo0[0],q0, oy0))));
    const float oi = fmaf(Wo1[3],q3, fmaf(Wo1[2],q2, fmaf(Wo1[1],q1, fmaf(Wo1[0],q0, oy1))));
    const float od = fmaf(Wo2[3],q3, fmaf(Wo2[2],q2, fmaf(Wo2[1],q1, fmaf(Wo2[0],q0, oy2))));

    float g = sigmoidf_(og);
    g = fminf(fmaxf(g, 0.05f), 0.95f);
    const float ig = sigmoidf_(oi);
    const float dt = tanhfast(od);
    cst = fmaf(fmaf(-0.9f, g, 0.9f), cst, ig*dt);
    const float pre = g * tanhfast(cst);

    // ---- fused LN + next-entry reductions (one parallel stage) ----
    const float s1 = full64(pre);
    const float s2 = full64(pre*pre);
    S0 = full64(WL[0]*pre);
    S1 = full64(WL[1]*pre);
    S2 = full64(WL[2]*pre);
    S3 = full64(WL[3]*pre);

    mu = s1 * (1.f/64.f);
    const float var = fmaf(s2, 1.f/64.f, -mu*mu);
    rstd = frsq(var + 1e-5f);

    h = fmaf((pre - mu)*rstd, lw, lb);
    op[(size_t)t*64] = h;
    w0 = 1.f;
  }

  // final hidden state h_T
  out[hToff + (size_t)blk*64 + lane] = h;
}

extern "C" void kernel_launch(void* const* d_in, const int* in_sizes, int n_in,
                              void* d_out, int out_size, void* d_ws, size_t ws_size,
                              hipStream_t stream)
{
  const float* x   = (const float*)d_in[0];
  const float* fw  = (const float*)d_in[1];
  const float* ew  = (const float*)d_in[2];
  const float* eb  = (const float*)d_in[3];
  const float* exw = (const float*)d_in[4];
  const float* exb = (const float*)d_in[5];
  const float* vw  = (const float*)d_in[6];
  const float* nw  = (const float*)d_in[7];
  const float* nb  = (const float*)d_in[8];

  const long long BT = in_sizes[0] / 128;           // B*T
  const int B = (int)((long long)out_size/64 - BT); // out = B*T*64 + B*64
  const int T = (int)(BT / B);

  qssm<<<B, 64, 0, stream>>>(x, fw, ew, eb, exw, exb, vw, nw, nb,
                             (float*)d_out, T, (long long)BT*64);
}

// Round 6
// 361.863 us; speedup vs baseline: 1.2465x; 1.0376x over previous
//
#include <hip/hip_runtime.h>

#define DEV static __device__ __forceinline__

struct Cx { float r, i; };
DEV Cx cmul(Cx a, Cx b){ Cx o; o.r = a.r*b.r - a.i*b.i; o.i = a.r*b.i + a.i*b.r; return o; }

// ---- DPP helpers (row = 16 lanes). Only modes proven passing (R1/R4). ----
template<int CTRL>
DEV float dppf(float x){
  int v = __builtin_amdgcn_update_dpp(0, __builtin_bit_cast(int, x), CTRL, 0xF, 0xF, true);
  return __builtin_bit_cast(float, v);
}
// sum over each 16-lane row; every lane of the row gets the full row sum
DEV float rowsum16(float v){
  v += dppf<0xB1>(v);    // quad_perm(1,0,3,2): xor 1
  v += dppf<0x4E>(v);    // quad_perm(2,3,0,1): xor 2
  v += dppf<0x124>(v);   // row_ror:4
  v += dppf<0x128>(v);   // row_ror:8
  return v;
}
// sum over the 4 stride-4 groups within a 16-lane row (keeps lane&3 fixed)
DEV float chunksum4(float v){
  v += dppf<0x124>(v);   // row_ror:4
  v += dppf<0x128>(v);   // row_ror:8
  return v;
}
DEV float rdl(float v, int l){
  return __builtin_bit_cast(float, __builtin_amdgcn_readlane(__builtin_bit_cast(int, v), l));
}
// full 64-lane sum, broadcast to all lanes (rowsum + 4 readlanes + adds)
DEV float full64(float v){
  float r = rowsum16(v);
  return (rdl(r,0) + rdl(r,16)) + (rdl(r,32) + rdl(r,48));
}

DEV float fexp(float x){ return __builtin_amdgcn_exp2f(x * 1.44269504088896341f); }
DEV float frcp(float x){ return __builtin_amdgcn_rcpf(x); }
DEV float frsq(float x){ return __builtin_amdgcn_rsqf(x); }
DEV float fsqrt_(float x){ return __builtin_amdgcn_sqrtf(x); }
DEV float sigmoidf_(float x){ return frcp(1.f + fexp(-x)); }
DEV float tanhfast(float x){ return 1.f - 2.f*frcp(1.f + fexp(2.f*x)); }

// qubit i <-> bit (3-i) of the 16-amplitude index.
__global__ void __launch_bounds__(64) qssm(
  const float* __restrict__ x,  const float* __restrict__ fw,
  const float* __restrict__ ew, const float* __restrict__ eb,
  const float* __restrict__ exw,const float* __restrict__ exb,
  const float* __restrict__ vw, const float* __restrict__ nrw,
  const float* __restrict__ nrb,float* __restrict__ out,
  int T, long long hToff)
{
  const int lane = threadIdx.x;      // 0..63
  const int blk  = blockIdx.x;       // batch element
  const int s    = lane & 15;        // position within 16-row
  const int r    = lane >> 4;        // row
  const int k    = 4*r + (lane & 3); // amplitude this lane owns (F-matvec)
  const int c    = (lane >> 2) & 3;  // j-chunk this lane sums

  // ---------- build fixed circuit matrix M (16x16 complex) once ----------
  __shared__ float MrS[16][16];
  __shared__ float MiS[16][16];
  if (lane < 16){
    const int j = lane;              // simulate column j
    float w2[2][3][4];
    #pragma unroll
    for (int l=0;l<2;l++)
      #pragma unroll
      for (int g=0;g<3;g++)
        #pragma unroll
        for (int i=0;i<4;i++) w2[l][g][i] = 0.5f * vw[(l*3+g)*4+i];
    float sr[16], si[16];
    #pragma unroll
    for (int n=0;n<16;n++){ sr[n] = (n==j)?1.f:0.f; si[n]=0.f; }
    #pragma unroll
    for (int l=0;l<2;l++){
      #pragma unroll
      for (int cq=0;cq<4;cq++){
        const int tq=(cq+1)&3, mc=1<<(3-cq), mt=1<<(3-tq);
        #pragma unroll
        for (int n=0;n<16;n++){
          if ((n&mc) && !(n&mt)){
            const int n1 = n|mt;
            float tr=sr[n], ti=si[n];
            sr[n]=sr[n1]; si[n]=si[n1];
            sr[n1]=tr;    si[n1]=ti;
          }
        }
      }
      #pragma unroll
      for (int i=0;i<4;i++){
        const int m=1<<(3-i);
        const float cx=cosf(w2[l][0][i]), sx=sinf(w2[l][0][i]);
        const float cy=cosf(w2[l][1][i]), sy=sinf(w2[l][1][i]);
        const float cz=cosf(w2[l][2][i]), sz=sinf(w2[l][2][i]);
        #pragma unroll
        for (int n=0;n<16;n++){
          if (!(n&m)){
            const int n1=n|m;
            float a0r=sr[n], a0i=si[n], a1r=sr[n1], a1i=si[n1];
            float b0r = cx*a0r + sx*a1i, b0i = cx*a0i - sx*a1r;
            float b1r = sx*a0i + cx*a1r, b1i = -sx*a0r + cx*a1i;
            float c0r = cy*b0r - sy*b1r, c0i = cy*b0i - sy*b1i;
            float c1r = sy*b0r + cy*b1r, c1i = sy*b0i + cy*b1i;
            sr[n]  = cz*c0r + sz*c0i;  si[n]  = cz*c0i - sz*c0r;
            sr[n1] = cz*c1r - sz*c1i;  si[n1] = cz*c1i + sz*c1r;
          }
        }
      }
    }
    #pragma unroll
    for (int n=0;n<16;n++){ MrS[n][j]=sr[n]; MiS[n][j]=si[n]; }
  }
  __syncthreads();

  // M fragment: row k, columns 4c..4c+3
  float Mr[4], Mi[4];
  #pragma unroll
  for (int m=0;m<4;m++){ Mr[m]=MrS[k][4*c+m]; Mi[m]=MiS[k][4*c+m]; }

  // ---------- per-lane weight registers ----------
  // entry row r (=qubit), x-cols 8s..8s+7, feature scale folded in
  float Wx[8];
  #pragma unroll
  for (int m=0;m<8;m++){
    const int col = 8*s+m;
    Wx[m] = ew[r*192 + col] * fexp(fw[col]);
  }
  const float e0b = eb[0], e1b = eb[1], e2b = eb[2], e3b = eb[3];

  // entry h-columns folded through LayerNorm:
  // hdot_q = rstd*(S_q - mu*C1_q) + C2_q,  S_q = sum(Wh_q*lw*pre)
  const float lw = nrw[lane], lb = nrb[lane];
  float WL[4], C1[4], C2[4];
  #pragma unroll
  for (int q=0;q<4;q++){
    const float whq = ew[q*192 + 128 + lane];
    WL[q] = whq * lw;
    C1[q] = full64(WL[q]);
    C2[q] = full64(whq * lb);
  }

  // exit rows: lane -> g_lane, i_lane, d_lane
  float Wo0[4], Wo1[4], Wo2[4];
  #pragma unroll
  for (int m=0;m<4;m++){
    Wo0[m] = exw[(lane      )*4+m];
    Wo1[m] = exw[(64  + lane)*4+m];
    Wo2[m] = exw[(128 + lane)*4+m];
  }
  const float bo0 = exb[lane], bo1 = exb[64+lane], bo2 = exb[128+lane];

  // pre-scaled Z-expectation signs (±0.25: each p_k appears 4x in its row)
  const float sg0 = (lane & 32) ? -0.25f : 0.25f;   // k bit3
  const float sg1 = (lane & 16) ? -0.25f : 0.25f;   // k bit2
  const float sg2 = (lane &  2) ? -0.25f : 0.25f;   // k bit1
  const float sg3 = (lane &  1) ? -0.25f : 0.25f;   // k bit0

  const float* xq = x + (size_t)blk * T * 128 + 8*s;  // lane's x column base
  float* op = out + (size_t)blk * T * 64 + lane;

  // recurrent state
  float S0=0.f, S1=0.f, S2=0.f, S3=0.f;   // sum WL_q * pre
  float mu=0.f, rstd=0.f, w0=0.f;         // LN scalars (w0 gates C2 on step 0)
  float cst=0.f, h=0.f;
  float Yx0, Yx1, Yx2, Yx3;

  // ---- preamble: Yx(0) from x(0); prime xrA = x(1) ----
  float xrA[8], xrB[8];
  {
    float xr[8];
    #pragma unroll
    for (int m=0;m<8;m++) xr[m] = xq[m];
    float d0 = fmaf(Wx[1],xr[1], Wx[0]*xr[0]);
    float d1 = fmaf(Wx[3],xr[3], Wx[2]*xr[2]);
    float d2 = fmaf(Wx[5],xr[5], Wx[4]*xr[4]);
    float d3 = fmaf(Wx[7],xr[7], Wx[6]*xr[6]);
    const float rs = rowsum16((d0+d1)+(d2+d3));
    Yx0 = rdl(rs, 0) + e0b; Yx1 = rdl(rs,16) + e1b;
    Yx2 = rdl(rs,32) + e2b; Yx3 = rdl(rs,48) + e3b;
  }
  #pragma unroll
  for (int m=0;m<8;m++) xrA[m] = xq[128 + m];   // x(1)

  // STEP(TCUR, XU, XL): top issues loads x(TCUR+2)->XL; bottom consumes XU(=x(TCUR+1)).
  // NOTE: inner copy of the loop counter is named t_ (macro hygiene — R5's bug
  // was `const int t = (t);` self-initialization via shadowing).
#define STEP(TCUR, XU, XL)                                                         \
  {                                                                                \
    const int t_ = (TCUR);                                                         \
    /* y_q = Yx_q + hdot_q (LN-folded) */                                          \
    const float y0 = Yx0 + fmaf(w0, C2[0], rstd*fmaf(-mu, C1[0], S0));             \
    const float y1 = Yx1 + fmaf(w0, C2[1], rstd*fmaf(-mu, C1[1], S1));             \
    const float y2 = Yx2 + fmaf(w0, C2[2], rstd*fmaf(-mu, C1[2], S2));             \
    const float y3 = Yx3 + fmaf(w0, C2[3], rstd*fmaf(-mu, C1[3], S3));             \
    /* issue prefetch loads for t_+2 (consumed 2 steps from now) */                \
    {                                                                              \
      const int tn = (t_+2 < T) ? (t_+2) : (T-1);                                  \
      const float* xsrc = xq + (size_t)tn*128;                                     \
      _Pragma("unroll")                                                            \
      for (int m=0;m<8;m++) XL[m] = xsrc[m];                                       \
    }                                                                              \
    /* exit y-part (runs parallel with VQC chain) */                               \
    const float oy0 = fmaf(Wo0[3],y3, fmaf(Wo0[2],y2, fmaf(Wo0[1],y1, fmaf(Wo0[0],y0, bo0)))); \
    const float oy1 = fmaf(Wo1[3],y3, fmaf(Wo1[2],y2, fmaf(Wo1[1],y1, fmaf(Wo1[0],y0, bo1)))); \
    const float oy2 = fmaf(Wo2[3],y3, fmaf(Wo2[2],y2, fmaf(Wo2[1],y1, fmaf(Wo2[0],y0, bo2)))); \
    /* encoded qubit vectors, phase-rotated so the |0> comp is real */             \
    float a0_,a1_,a2_,a3_;  Cx b0_,b1_,b2_,b3_;                                    \
    {                                                                              \
      auto mkv = [&](float u, float& a, Cx& b){                                    \
        const float r2 = u*u;                                                      \
        const float c1 = frsq(fmaf(u,u,1.f));                                      \
        const float tt = (0.5f*u)*c1;                                              \
        a = fsqrt_(fmaxf(0.5f - tt, 0.f));                                         \
        const float bb = fsqrt_(0.5f + tt);                                        \
        const float cp = frsq(fmaf(r2,r2,1.f));                                    \
        const float sp = r2*cp;                                                    \
        b.r = bb*cp; b.i = bb*sp;                                                  \
      };                                                                           \
      mkv(y0,a0_,b0_); mkv(y1,a1_,b1_); mkv(y2,a2_,b2_); mkv(y3,a3_,b3_);          \
    }                                                                              \
    /* psi0[j], j = 4c + m */                                                      \
    Cx sel0, sel1;                                                                 \
    sel0.r = (lane & 8) ? b0_.r : a0_;  sel0.i = (lane & 8) ? b0_.i : 0.f;         \
    sel1.r = (lane & 4) ? b1_.r : a1_;  sel1.i = (lane & 4) ? b1_.i : 0.f;         \
    const Cx A = cmul(sel0, sel1);                                                 \
    Cx B0, B1, B2, B3;                                                             \
    B0.r = a2_*a3_;            B0.i = 0.f;                                         \
    B1.r = a2_*b3_.r;          B1.i = a2_*b3_.i;                                   \
    B2.r = b2_.r*a3_;          B2.i = b2_.i*a3_;                                   \
    B3 = cmul(b2_, b3_);                                                           \
    const Cx p0 = cmul(A,B0), p1 = cmul(A,B1), p2 = cmul(A,B2), p3 = cmul(A,B3);   \
    /* F_k partial over j=4c..4c+3, then in-row chunk reduction (DPP only) */      \
    float t0r = fmaf(-p0.i, Mi[0], p0.r*Mr[0]);                                    \
    float t1r = fmaf(-p1.i, Mi[1], p1.r*Mr[1]);                                    \
    float t2r = fmaf(-p2.i, Mi[2], p2.r*Mr[2]);                                    \
    float t3r = fmaf(-p3.i, Mi[3], p3.r*Mr[3]);                                    \
    float t0i = fmaf( p0.i, Mr[0], p0.r*Mi[0]);                                    \
    float t1i = fmaf( p1.i, Mr[1], p1.r*Mi[1]);                                    \
    float t2i = fmaf( p2.i, Mr[2], p2.r*Mi[2]);                                    \
    float t3i = fmaf( p3.i, Mr[3], p3.r*Mi[3]);                                    \
    const float Fr = chunksum4((t0r+t1r)+(t2r+t3r));                               \
    const float Fi = chunksum4((t0i+t1i)+(t2i+t3i));                               \
    const float p = fmaf(Fr,Fr, Fi*Fi);                                            \
    /* Z expectations: signed full-64 sums */                                      \
    const float q0 = full64(sg0*p);                                                \
    const float q1 = full64(sg1*p);                                                \
    const float q2 = full64(sg2*p);                                                \
    const float q3 = full64(sg3*p);                                                \
    /* exit q-part + gates */                                                      \
    const float og = fmaf(Wo0[3],q3, fmaf(Wo0[2],q2, fmaf(Wo0[1],q1, fmaf(Wo0[0],q0, oy0)))); \
    const float oi = fmaf(Wo1[3],q3, fmaf(Wo1[2],q2, fmaf(Wo1[1],q1, fmaf(Wo1[0],q0, oy1)))); \
    const float od = fmaf(Wo2[3],q3, fmaf(Wo2[2],q2, fmaf(Wo2[1],q1, fmaf(Wo2[0],q0, oy2)))); \
    float g = sigmoidf_(og);                                                       \
    g = fminf(fmaxf(g, 0.05f), 0.95f);                                             \
    const float ig = sigmoidf_(oi);                                                \
    const float dt = tanhfast(od);                                                 \
    cst = fmaf(fmaf(-0.9f, g, 0.9f), cst, ig*dt);                                  \
    const float pre = g * tanhfast(cst);                                           \
    /* fused LN + next-entry reductions (6 independent reduces) */                 \
    const float s1 = full64(pre);                                                  \
    const float s2 = full64(pre*pre);                                              \
    S0 = full64(WL[0]*pre);                                                        \
    S1 = full64(WL[1]*pre);                                                        \
    S2 = full64(WL[2]*pre);                                                        \
    S3 = full64(WL[3]*pre);                                                        \
    mu = s1 * (1.f/64.f);                                                          \
    const float var = fmaf(s2, 1.f/64.f, -mu*mu);                                  \
    rstd = frsq(var + 1e-5f);                                                      \
    h = fmaf((pre - mu)*rstd, lw, lb);                                             \
    op[(size_t)t_*64] = h;                                                         \
    w0 = 1.f;                                                                      \
    /* bottom: next Yx from XU (=x(t_+1)); loaded ~2 steps ago -> no stall */      \
    {                                                                              \
      float d0 = fmaf(Wx[1],XU[1], Wx[0]*XU[0]);                                   \
      float d1 = fmaf(Wx[3],XU[3], Wx[2]*XU[2]);                                   \
      float d2 = fmaf(Wx[5],XU[5], Wx[4]*XU[4]);                                   \
      float d3 = fmaf(Wx[7],XU[7], Wx[6]*XU[6]);                                   \
      const float rs = rowsum16((d0+d1)+(d2+d3));                                  \
      Yx0 = rdl(rs, 0) + e0b; Yx1 = rdl(rs,16) + e1b;                              \
      Yx2 = rdl(rs,32) + e2b; Yx3 = rdl(rs,48) + e3b;                              \
    }                                                                              \
  }

  for (int t=0; t<T; t+=2){
    STEP(t,   xrA, xrB);
    STEP(t+1, xrB, xrA);
  }
#undef STEP

  // final hidden state h_T
  out[hToff + (size_t)blk*64 + lane] = h;
}

extern "C" void kernel_launch(void* const* d_in, const int* in_sizes, int n_in,
                              void* d_out, int out_size, void* d_ws, size_t ws_size,
                              hipStream_t stream)
{
  const float* x   = (const float*)d_in[0];
  const float* fw  = (const float*)d_in[1];
  const float* ew  = (const float*)d_in[2];
  const float* eb  = (const float*)d_in[3];
  const float* exw = (const float*)d_in[4];
  const float* exb = (const float*)d_in[5];
  const float* vw  = (const float*)d_in[6];
  const float* nw  = (const float*)d_in[7];
  const float* nb  = (const float*)d_in[8];

  const long long BT = in_sizes[0] / 128;           // B*T
  const int B = (int)((long long)out_size/64 - BT); // out = B*T*64 + B*64
  const int T = (int)(BT / B);

  qssm<<<B, 64, 0, stream>>>(x, fw, ew, eb, exw, exb, vw, nw, nb,
                             (float*)d_out, T, (long long)BT*64);
}